// Round 2
// baseline (66.296 us; speedup 1.0000x reference)
//
#include <hip/hip_runtime.h>

#define BOLTZMAN 0.001987191f

// Setup: build the two length-64 coefficient vectors in d_ws.
//   A[t] = -scale * mk[64-t]  (t=1..63),  A[0] = -scale * mk[0]   (coef for v[i])
//   B[t] =  h1[64-t]          (t=1..63),  B[0] =  h1[0]           (coef for w_new[i])
// where mk[k] = autocorrelation of h1 at lag k, scale = mass[0]*kB*T.
__global__ void gle_setup(const float* __restrict__ h,
                          const float* __restrict__ mass,
                          const int* __restrict__ T,
                          float* __restrict__ coef) {
    __shared__ float sh[64];
    int t = threadIdx.x;
    if (t < 64) sh[t] = h[t];
    __syncthreads();
    if (t < 64) {
        float scale = mass[0] * BOLTZMAN * (float)T[0];
        int lag = (t == 0) ? 0 : (64 - t);
        float s = 0.0f;
        for (int k = 0; k + lag < 64; ++k) s += sh[k] * sh[k + lag];
        coef[t]      = -scale * s;                       // A[t]
        coef[64 + t] = (t == 0) ? sh[0] : sh[64 - t];    // B[t]
    }
}

__device__ __forceinline__ float rowdot(const float4 a, const float4 b,
                                        const float4 x, const float4 y) {
    return a.x * x.x + a.y * x.y + a.z * x.z + a.w * x.w
         + b.x * y.x + b.y * y.y + b.z * y.z + b.w * y.w;
}

// Main: 16 lanes per row-group; each group processes 4 rows (grid-stride at
// stride S = total groups). All 8 stream float4 loads issued up front ->
// 8 KB independent loads in flight per wave; 4 independent shuffle-reduce
// chains. Per load instruction a wave still covers 4 consecutive rows
// = 1 KiB contiguous.
__global__ void __launch_bounds__(256) gle_main(
    const float* __restrict__ v, const float* __restrict__ w_new,
    const float* __restrict__ v_list, const float* __restrict__ w_list,
    const float* __restrict__ coef, float* __restrict__ out, int nrows)
{
    const int c = threadIdx.x & 15;
    const int g = blockIdx.x * 16 + (threadIdx.x >> 4);
    const int S = gridDim.x * 16;            // total 16-lane groups

    const float4 a = ((const float4*)coef)[c];
    const float4 b = ((const float4*)(coef + 64))[c];

    const int r0 = g;
    const int r1 = g + S;
    const int r2 = g + 2 * S;
    const int r3 = g + 3 * S;

    if (r3 < nrows) {
        float4 x0 = ((const float4*)(v_list + (size_t)r0 * 64))[c];
        float4 y0 = ((const float4*)(w_list + (size_t)r0 * 64))[c];
        float4 x1 = ((const float4*)(v_list + (size_t)r1 * 64))[c];
        float4 y1 = ((const float4*)(w_list + (size_t)r1 * 64))[c];
        float4 x2 = ((const float4*)(v_list + (size_t)r2 * 64))[c];
        float4 y2 = ((const float4*)(w_list + (size_t)r2 * 64))[c];
        float4 x3 = ((const float4*)(v_list + (size_t)r3 * 64))[c];
        float4 y3 = ((const float4*)(w_list + (size_t)r3 * 64))[c];
        if (c == 0) {                         // ring slot 0 is dead
            x0.x = v[r0]; y0.x = w_new[r0];
            x1.x = v[r1]; y1.x = w_new[r1];
            x2.x = v[r2]; y2.x = w_new[r2];
            x3.x = v[r3]; y3.x = w_new[r3];
        }
        float s0 = rowdot(a, b, x0, y0);
        float s1 = rowdot(a, b, x1, y1);
        float s2 = rowdot(a, b, x2, y2);
        float s3 = rowdot(a, b, x3, y3);
        #pragma unroll
        for (int m = 1; m <= 8; m <<= 1) {    // 4 independent reduce chains
            s0 += __shfl_xor(s0, m);
            s1 += __shfl_xor(s1, m);
            s2 += __shfl_xor(s2, m);
            s3 += __shfl_xor(s3, m);
        }
        if (c == 0) {
            out[r0] = s0; out[r1] = s1; out[r2] = s2; out[r3] = s3;
        }
    } else {                                  // boundary groups
        for (int r = r0; r < nrows; r += S) {
            float4 x = ((const float4*)(v_list + (size_t)r * 64))[c];
            float4 y = ((const float4*)(w_list + (size_t)r * 64))[c];
            if (c == 0) { x.x = v[r]; y.x = w_new[r]; }
            float s = rowdot(a, b, x, y);
            #pragma unroll
            for (int m = 1; m <= 8; m <<= 1) s += __shfl_xor(s, m);
            if (c == 0) out[r] = s;
        }
    }
}

extern "C" void kernel_launch(void* const* d_in, const int* in_sizes, int n_in,
                              void* d_out, int out_size, void* d_ws, size_t ws_size,
                              hipStream_t stream) {
    const float* v      = (const float*)d_in[0];   // [N,3] f32
    const int*   T      = (const int*)d_in[1];     // scalar int
    /* d_in[2] = dt (unused) */
    const float* mass   = (const float*)d_in[3];   // [N,3] f32 (use [0])
    const float* h      = (const float*)d_in[4];   // [1,1,64] f32
    const float* v_list = (const float*)d_in[5];   // [3N,1,64] f32
    const float* w_list = (const float*)d_in[6];   // [3N,1,64] f32
    const float* w_new  = (const float*)d_in[7];   // [N,3] f32
    float* out  = (float*)d_out;                   // [N,3] f32
    float* coef = (float*)d_ws;                    // 128 floats

    int nrows = in_sizes[0];                       // 3N = 600000

    gle_setup<<<1, 64, 0, stream>>>(h, mass, T, coef);

    // Each block: 16 groups x 4 rows = 64 rows.
    int blocks = (nrows + 63) / 64;                // 9375 for nrows=600000
    gle_main<<<blocks, 256, 0, stream>>>(v, w_new, v_list, w_list, coef, out, nrows);
}

// Round 3
// 61.435 us; speedup vs baseline: 1.0791x; 1.0791x over previous
//
#include <hip/hip_runtime.h>

#define BOLTZMAN 0.001987191f

// Setup: build the two length-64 coefficient vectors in d_ws.
//   A[t] = -scale * mk[64-t]  (t=1..63),  A[0] = -scale * mk[0]   (coef for v[i])
//   B[t] =  h1[64-t]          (t=1..63),  B[0] =  h1[0]           (coef for w_new[i])
// where mk[k] = autocorrelation of h1 at lag k, scale = mass[0]*kB*T.
__global__ void gle_setup(const float* __restrict__ h,
                          const float* __restrict__ mass,
                          const int* __restrict__ T,
                          float* __restrict__ coef) {
    __shared__ float sh[64];
    int t = threadIdx.x;
    if (t < 64) sh[t] = h[t];
    __syncthreads();
    if (t < 64) {
        float scale = mass[0] * BOLTZMAN * (float)T[0];
        int lag = (t == 0) ? 0 : (64 - t);
        float s = 0.0f;
        for (int k = 0; k + lag < 64; ++k) s += sh[k] * sh[k + lag];
        coef[t]      = -scale * s;                       // A[t]
        coef[64 + t] = (t == 0) ? sh[0] : sh[64 - t];    // B[t]
    }
}

__device__ __forceinline__ float rowdot(const float4 a, const float4 b,
                                        const float4 x, const float4 y) {
    return a.x * x.x + a.y * x.y + a.z * x.z + a.w * x.w
         + b.x * y.x + b.y * y.y + b.z * y.z + b.w * y.w;
}

// Main: 16 lanes per group; each group handles TWO ADJACENT rows (2g, 2g+1).
// A wave (4 groups) issues 4 independent 1 KiB-contiguous load instructions
// covering one unbroken 2 KB span of each buffer; each 256-thread block owns
// one contiguous 8 KB span per buffer. ILP x2 over round 1 WITHOUT the
// round-2 stream scatter.
__global__ void __launch_bounds__(256) gle_main(
    const float* __restrict__ v, const float* __restrict__ w_new,
    const float* __restrict__ v_list, const float* __restrict__ w_list,
    const float* __restrict__ coef, float* __restrict__ out, int nrows)
{
    const int c = threadIdx.x & 15;
    const int g = blockIdx.x * 16 + (threadIdx.x >> 4);

    const float4 a = ((const float4*)coef)[c];
    const float4 b = ((const float4*)(coef + 64))[c];

    const int r0 = 2 * g;
    const int r1 = 2 * g + 1;
    if (r1 >= nrows) {                       // tail (nrows odd edge); r0 case
        if (r0 < nrows) {
            float4 x = ((const float4*)(v_list + (size_t)r0 * 64))[c];
            float4 y = ((const float4*)(w_list + (size_t)r0 * 64))[c];
            if (c == 0) { x.x = v[r0]; y.x = w_new[r0]; }
            float s = rowdot(a, b, x, y);
            #pragma unroll
            for (int m = 1; m <= 8; m <<= 1) s += __shfl_xor(s, m);
            if (c == 0) out[r0] = s;
        }
        return;
    }

    float4 x0 = ((const float4*)(v_list + (size_t)r0 * 64))[c];
    float4 y0 = ((const float4*)(w_list + (size_t)r0 * 64))[c];
    float4 x1 = ((const float4*)(v_list + (size_t)r1 * 64))[c];
    float4 y1 = ((const float4*)(w_list + (size_t)r1 * 64))[c];
    if (c == 0) {                            // ring slot 0 is dead
        x0.x = v[r0]; y0.x = w_new[r0];
        x1.x = v[r1]; y1.x = w_new[r1];
    }
    float s0 = rowdot(a, b, x0, y0);
    float s1 = rowdot(a, b, x1, y1);
    #pragma unroll
    for (int m = 1; m <= 8; m <<= 1) {       // 2 independent reduce chains
        s0 += __shfl_xor(s0, m);
        s1 += __shfl_xor(s1, m);
    }
    if (c == 0) { out[r0] = s0; out[r1] = s1; }
}

extern "C" void kernel_launch(void* const* d_in, const int* in_sizes, int n_in,
                              void* d_out, int out_size, void* d_ws, size_t ws_size,
                              hipStream_t stream) {
    const float* v      = (const float*)d_in[0];   // [N,3] f32
    const int*   T      = (const int*)d_in[1];     // scalar int
    /* d_in[2] = dt (unused) */
    const float* mass   = (const float*)d_in[3];   // [N,3] f32 (use [0])
    const float* h      = (const float*)d_in[4];   // [1,1,64] f32
    const float* v_list = (const float*)d_in[5];   // [3N,1,64] f32
    const float* w_list = (const float*)d_in[6];   // [3N,1,64] f32
    const float* w_new  = (const float*)d_in[7];   // [N,3] f32
    float* out  = (float*)d_out;                   // [N,3] f32
    float* coef = (float*)d_ws;                    // 128 floats

    int nrows = in_sizes[0];                       // 3N = 600000

    gle_setup<<<1, 64, 0, stream>>>(h, mass, T, coef);

    // Each block: 16 groups x 2 adjacent rows = 32 rows.
    int blocks = (nrows + 31) / 32;                // 18750 for nrows=600000
    gle_main<<<blocks, 256, 0, stream>>>(v, w_new, v_list, w_list, coef, out, nrows);
}